// Round 2
// 2605.117 us; speedup vs baseline: 2.7499x; 2.7499x over previous
//
#include <hip/hip_runtime.h>
#include <hip/hip_bf16.h>

typedef __bf16 bf16_t;
typedef __attribute__((ext_vector_type(8))) __bf16 bf16x8;
typedef __attribute__((ext_vector_type(4))) float f32x4;

#define B_  128
#define T_  512
#define H_  1024

// ---------------- P0: convert weights to bf16, init h0, zero barrier counters
__global__ void prep_kernel(const float* __restrict__ Wx, const float* __restrict__ Wh,
                            const float* __restrict__ Wo, const float* __restrict__ hinit,
                            bf16_t* __restrict__ Wxb, bf16_t* __restrict__ Whb,
                            bf16_t* __restrict__ Wob, bf16_t* __restrict__ h0,
                            unsigned* __restrict__ cnt)
{
    unsigned i = blockIdx.x * 256u + threadIdx.x;   // grid = 4096*256 = 1M = H*H exactly
    if (i < 512u) cnt[i] = 0u;                      // counters padded: 8 groups x 64 stride
    Wxb[i] = (bf16_t)Wx[i];
    Whb[i] = (bf16_t)Wh[i];
    Wob[i] = (bf16_t)Wo[i];
    if (i < (unsigned)(B_ * H_)) h0[i] = (bf16_t)hinit[i];
}

// ---------------- shared GEMM: C[M,1024] = cvt(A_f32) @ Bw[1024,1024]^T + bias
// split=1: two passes (bf16 hi + bf16 lo of A) for ~fp32-quality A (used for P_tab)
__global__ void __launch_bounds__(256, 2) gemm_bf16(
    const float* __restrict__ A,    // [Mt*128][1024] fp32
    const bf16_t* __restrict__ Bw,  // [1024][1024] bf16, row n holds W[n][k]
    const float* __restrict__ bias, // [1024] or nullptr
    float* __restrict__ C,          // [Mt*128][1024] fp32
    int split)
{
    __shared__ bf16_t Al[128][72];
    __shared__ bf16_t Bl[128][72];
    const int tid = threadIdx.x;
    const int w = tid >> 6, l = tid & 63;
    const int wm = w >> 1, wn = w & 1;
    const int lm = l & 15, lq = l >> 4;
    const int tileM = blockIdx.x >> 3, tileN = blockIdx.x & 7;
    const int srow = tid >> 1, scol = (tid & 1) * 32;
    const float*  Ab = A  + (size_t)(tileM * 128 + srow) * 1024 + scol;
    const bf16_t* Bb = Bw + (size_t)(tileN * 128 + srow) * 1024 + scol;
    f32x4 acc[4][4] = {};

    for (int pass = 0; pass <= split; ++pass) {
        for (int kt = 0; kt < 16; ++kt) {
            const int k0 = kt * 64;
            // stage A tile (fp32 -> bf16 hi or lo residual)
            float fv[32];
            #pragma unroll
            for (int j = 0; j < 8; ++j)
                *(float4*)(fv + 4 * j) = *(const float4*)(Ab + k0 + 4 * j);
            bf16_t av[32];
            #pragma unroll
            for (int e = 0; e < 32; ++e) {
                float f = fv[e];
                bf16_t hi = (bf16_t)f;
                av[e] = (pass == 0) ? hi : (bf16_t)(f - (float)hi);
            }
            #pragma unroll
            for (int j = 0; j < 4; ++j)
                *(bf16x8*)(&Al[srow][scol + 8 * j]) = *(const bf16x8*)(av + 8 * j);
            // stage B tile (bf16 copy)
            #pragma unroll
            for (int j = 0; j < 4; ++j)
                *(bf16x8*)(&Bl[srow][scol + 8 * j]) = *(const bf16x8*)(Bb + k0 + 8 * j);
            __syncthreads();
            #pragma unroll
            for (int kk = 0; kk < 2; ++kk) {
                bf16x8 af[4], bfr[4];
                #pragma unroll
                for (int i = 0; i < 4; ++i)
                    af[i] = *(const bf16x8*)(&Al[wm * 64 + i * 16 + lm][kk * 32 + lq * 8]);
                #pragma unroll
                for (int i = 0; i < 4; ++i)
                    bfr[i] = *(const bf16x8*)(&Bl[wn * 64 + i * 16 + lm][kk * 32 + lq * 8]);
                #pragma unroll
                for (int mt = 0; mt < 4; ++mt)
                    #pragma unroll
                    for (int nt = 0; nt < 4; ++nt)
                        acc[mt][nt] = __builtin_amdgcn_mfma_f32_16x16x32_bf16(
                            af[mt], bfr[nt], acc[mt][nt], 0, 0, 0);
            }
            __syncthreads();
        }
    }
    // epilogue: D lane map col = l&15, row = (l>>4)*4 + r   [m89-verified]
    const int gm0 = tileM * 128 + wm * 64;
    const int gn0 = tileN * 128 + wn * 64;
    float bv[4] = {0.f, 0.f, 0.f, 0.f};
    if (bias) {
        #pragma unroll
        for (int nt = 0; nt < 4; ++nt) bv[nt] = bias[gn0 + nt * 16 + lm];
    }
    #pragma unroll
    for (int mt = 0; mt < 4; ++mt)
        #pragma unroll
        for (int nt = 0; nt < 4; ++nt)
            #pragma unroll
            for (int r = 0; r < 4; ++r) {
                const int gm = gm0 + mt * 16 + lq * 4 + r;
                const int gn = gn0 + nt * 16 + lm;
                C[(size_t)gm * 1024 + gn] = acc[mt][nt][r] + bv[nt];
            }
}

// ---------------- P2: persistent recurrence kernel (cooperative, 128 WGs)
// WG = (batch-group of 16 rows) x (i-group of 64 outputs); wave owns 16 outputs,
// holds its Wh slice [16 x 1024] bf16 in 128 VGPRs. Per-batch-group 16-WG barrier.
//
// Coherence scheme: only hbuf + counters cross WGs. They are accessed with
// relaxed AGENT-scope ops (sc1-flagged: bypass L1/L2, coherent at Infinity Cache).
// NO release fetch_add (no buffer_wbl2) and NO acquire fence (no buffer_inv) —
// the per-step whole-L2 writeback+invalidate was ~95% of the step cost and also
// evicted Ptab/x from L2 every step (467 MB refetch). Ordering: the explicit
// s_waitcnt vmcnt(0) before the arrival atomic guarantees all sc1 h-stores are
// acked at the coherence point before the counter increments.
__global__ void __launch_bounds__(256, 1) rnn_steps(
    const int* __restrict__ x,      // [128][512]
    const float* __restrict__ Ptab, // [1024][1024] fp32: embed@Wx^T + bx
    const bf16_t* __restrict__ Whb, // [1024][1024] bf16
    const float* __restrict__ bh,   // [1024]
    bf16_t* __restrict__ hbuf,      // [2][128][1024] bf16 ping-pong (IC-coherent)
    float* __restrict__ h_e,        // [128][512][1024] output
    unsigned* __restrict__ counters)// [8*64] padded, 256B per group
{
    const int bg = blockIdx.x >> 4;   // 0..7
    const int ig = blockIdx.x & 15;   // 0..15
    const int tid = threadIdx.x;
    const int w = tid >> 6, l = tid & 63;
    const int lm = l & 15, lq = l >> 4;
    const int b0 = bg * 16;
    const int i0 = ig * 64 + w * 16;
    __shared__ bf16_t hl[16][1032];   // h_prev tile, padded rows

    // persistent Wh fragments: B-op lane map n=l&15 (row of Wh), k=(l>>4)*8+j
    bf16x8 bfrag[32];
    {
        const bf16_t* wr = Whb + (size_t)(i0 + lm) * 1024 + lq * 8;
        #pragma unroll
        for (int s = 0; s < 32; ++s)
            bfrag[s] = *(const bf16x8*)(wr + s * 32);
    }
    const float biasv = bh[i0 + lm];
    unsigned* cnt = counters + bg * 64;   // own 256B line per batch group

    // xp prefetch double-buffer: xpv for step t, xpn loaded for t+1 during step t
    float xpv[4];
    #pragma unroll
    for (int r = 0; r < 4; ++r) {
        const int m = lq * 4 + r;
        xpv[r] = Ptab[(size_t)x[(b0 + m) * T_] * 1024 + i0 + lm];
    }

    for (int t = 0; t < T_; ++t) {
        // stage h_prev[b0..b0+15][0..1023] into LDS via agent-scope 8B loads
        // (reads Infinity Cache directly — coherent with peers' sc1 stores)
        bf16_t* hsrc = hbuf + (size_t)(t & 1) * (B_ * H_) + (size_t)b0 * 1024;
        unsigned long long hv[16];
        #pragma unroll
        for (int j = 0; j < 16; ++j) {
            const int c = tid + 256 * j;   // 0..4095 8B-chunks
            hv[j] = __hip_atomic_load((unsigned long long*)hsrc + c,
                                      __ATOMIC_RELAXED, __HIP_MEMORY_SCOPE_AGENT);
        }
        #pragma unroll
        for (int j = 0; j < 16; ++j) {
            const int c = tid + 256 * j;
            const int row = c >> 8;            // 256 chunks per 1024-col row
            const int col = (c & 255) * 4;
            *(unsigned long long*)(&hl[row][col]) = hv[j];
        }
        __syncthreads();

        // prefetch next step's xp (h-independent; hides under MFMA + barrier)
        float xpn[4] = {0.f, 0.f, 0.f, 0.f};
        if (t + 1 < T_) {
            #pragma unroll
            for (int r = 0; r < 4; ++r) {
                const int m = lq * 4 + r;
                xpn[r] = Ptab[(size_t)x[(b0 + m) * T_ + t + 1] * 1024 + i0 + lm];
            }
        }

        f32x4 acc = {0.f, 0.f, 0.f, 0.f};
        #pragma unroll
        for (int s = 0; s < 32; ++s) {
            const bf16x8 af = *(const bf16x8*)(&hl[lm][s * 32 + lq * 8]);
            acc = __builtin_amdgcn_mfma_f32_16x16x32_bf16(af, bfrag[s], acc, 0, 0, 0);
        }

        // epilogue: tanh; h_e nontemporal (don't thrash L2 vs Ptab);
        // hbuf via sc1 short stores (write-through to IC, no L2 dirty state)
        bf16_t* hdst = hbuf + (size_t)((t + 1) & 1) * (B_ * H_) + (size_t)b0 * 1024;
        #pragma unroll
        for (int r = 0; r < 4; ++r) {
            const int m = lq * 4 + r;
            const float v = tanhf(acc[r] + xpv[r] + biasv);
            __builtin_nontemporal_store(v,
                &h_e[((size_t)(b0 + m) * T_ + t) * 1024 + i0 + lm]);
            const bf16_t hb = (bf16_t)v;
            const unsigned hu = (unsigned)__builtin_bit_cast(unsigned short, hb);
            asm volatile("global_store_short %0, %1, off sc1"
                         :: "v"(hdst + m * 1024 + i0 + lm), "v"(hu) : "memory");
        }
        // drain all stores (incl. inline-asm sc1 stores) to the coherence point
        asm volatile("s_waitcnt vmcnt(0)" ::: "memory");
        __syncthreads();

        if (tid == 0) {
            __hip_atomic_fetch_add(cnt, 1u, __ATOMIC_RELAXED, __HIP_MEMORY_SCOPE_AGENT);
            const unsigned target = 16u * (unsigned)(t + 1);
            while (__hip_atomic_load(cnt, __ATOMIC_RELAXED, __HIP_MEMORY_SCOPE_AGENT) < target)
                __builtin_amdgcn_s_sleep(1);
        }
        __syncthreads();   // in-order issue: post-barrier sc1 loads can't start early

        #pragma unroll
        for (int r = 0; r < 4; ++r) xpv[r] = xpn[r];
    }
}

extern "C" void kernel_launch(void* const* d_in, const int* in_sizes, int n_in,
                              void* d_out, int out_size, void* d_ws, size_t ws_size,
                              hipStream_t stream)
{
    (void)in_sizes; (void)n_in; (void)out_size; (void)ws_size;
    const int*   x     = (const int*)  d_in[0];
    const float* hinit = (const float*)d_in[1];
    const float* emb   = (const float*)d_in[2];
    const float* Wx    = (const float*)d_in[3];
    const float* bx    = (const float*)d_in[4];
    const float* Wh    = (const float*)d_in[5];
    const float* bh    = (const float*)d_in[6];
    const float* Wo    = (const float*)d_in[7];
    const float* bo    = (const float*)d_in[8];
    float* h_e = (float*)d_out;                       // [128*512*1024]
    float* y   = h_e + (size_t)B_ * T_ * H_;          // [128*512*1024]

    char* ws = (char*)d_ws;                           // ~11 MB used
    bf16_t*  Whb  = (bf16_t*)(ws);                    // 2 MB
    bf16_t*  Wob  = (bf16_t*)(ws + ((size_t)2 << 20));// 2 MB
    bf16_t*  Wxb  = (bf16_t*)(ws + ((size_t)4 << 20));// 2 MB
    float*   Ptab = (float*) (ws + ((size_t)6 << 20));// 4 MB
    bf16_t*  hbuf = (bf16_t*)(ws + ((size_t)10 << 20));// 512 KB
    unsigned* cnt = (unsigned*)(ws + ((size_t)11 << 20)); // 2 KB (8 groups x 256B)

    // P0: bf16 weight copies, h0, zero counters
    prep_kernel<<<4096, 256, 0, stream>>>(Wx, Wh, Wo, hinit, Wxb, Whb, Wob, hbuf, cnt);
    // P1: P_tab = embed @ Wx^T + bx  (split-precision bf16 MFMA, fp32 out)
    gemm_bf16<<<64, 256, 0, stream>>>(emb, Wxb, bx, Ptab, 1);
    // P2: 512 recurrence steps in one cooperative kernel
    {
        const int* xa = x; const float* pa = Ptab; const bf16_t* wa = Whb;
        const float* ba = bh; bf16_t* ha = hbuf; float* hea = h_e; unsigned* ca = cnt;
        void* args[] = { (void*)&xa, (void*)&pa, (void*)&wa, (void*)&ba,
                         (void*)&ha, (void*)&hea, (void*)&ca };
        hipLaunchCooperativeKernel((const void*)rnn_steps, dim3(128), dim3(256),
                                   args, 0, stream);
    }
    // P3: y = h_e @ Wo^T + bo
    gemm_bf16<<<4096, 256, 0, stream>>>(h_e, Wob, bo, y, 0);
}